// Round 13
// baseline (128.557 us; speedup 1.0000x reference)
//
#include <hip/hip_runtime.h>
#include <stdint.h>

#define HH 64
#define WW 64
#define PIN 64
#define POUT 64
#define NFEAT 54
#define OSLAB 221184   // bytes per o-half: 54 feat * 4096 (32 o x 64 c fp16)
#define HSLAB 110592   // half slab: 27 features * 4096

typedef _Float16 half8 __attribute__((ext_vector_type(8)));
typedef _Float16 half4 __attribute__((ext_vector_type(4)));
typedef float f32x4 __attribute__((ext_vector_type(4)));
typedef float f32x16 __attribute__((ext_vector_type(16)));

// feature enumeration tables: f -> (k,l)
__constant__ const int KT[54] = {0,0,0,0,0,0,0,0,0, 1,1,1,1,1,1,1,1,1, 2,2,2,2,2,2,2,2,
                                 3,3,3,3,3,3,3, 4,4,4,4,4,4, 5,5,5,5,5, 6,6,6,6, 7,7,7, 8,8, 9};
__constant__ const int LT[54] = {1,2,3,4,5,6,7,8,9, 1,2,3,4,5,6,7,8,9, 2,3,4,5,6,7,8,9,
                                 3,4,5,6,7,8,9, 4,5,6,7,8,9, 5,6,7,8,9, 6,7,8,9, 7,8,9, 8,9, 9};

// ---------------- filter prep ----------------
// Fragment-order, o-half-major:
//   byte(f,o,c) = (o>>5)*OSLAB + f*4096 + (c>>4)*1024 + ((o&31)+32*((c>>3)&1))*16 + (c&7)*2
// One feature = 4096 B (4 kcq x 64 lanes x 16 B). Wave (kc-half kch) reads frag q of
// feature-slot i at smB + i*4096 + (kch*2+q)*1024 + lane*16.
__global__ void prep_filters(const float* __restrict__ f, const float* __restrict__ bias,
                             _Float16* __restrict__ fprep, float* __restrict__ fconst) {
    if (blockIdx.x == 108) {
        int o = threadIdx.x;
        if (o < POUT) {
            float s = bias[o];
            for (int c = 0; c < PIN; ++c) s += f[(size_t)(o * PIN + c) * 100];
            fconst[o] = s;
        }
        return;
    }
    int tid = blockIdx.x * 256 + threadIdx.x;   // 0..27647 = 54*64*8
    int feat = tid >> 9;
    int rem = tid & 511;
    int o = rem >> 3;
    int cg = rem & 7;                           // c = cg*8 + jj
    int k = KT[feat], l = LT[feat];

    half8 chunk;
    #pragma unroll
    for (int jj = 0; jj < 8; ++jj) {
        int c = cg * 8 + jj;
        const float* fc = f + (size_t)(o * PIN + c) * 100;
        float v;
        if (k == 0)      v = fc[l] + fc[l * 10];
        else if (k == l) v = fc[k * 10 + k];
        else             v = fc[k * 10 + l] + fc[l * 10 + k];
        chunk[jj] = (_Float16)v;
    }
    size_t byte = (size_t)(o >> 5) * OSLAB + (size_t)feat * 4096 + (cg >> 1) * 1024
                + ((o & 31) + 32 * (cg & 1)) * 16;
    *(half8*)((char*)fprep + byte) = chunk;
}

// ---------------- main MFMA kernel ----------------
// grid 512 = oh(2) x b(8) x rowpair(32), XCD-swizzled; block 512 thr = 8 waves =
// 4 m-tiles (32 px: row j x w-half) x 2 kc-halves (K=32, 2 chained MFMAs).
// B: one o-half slab (221KB) staged in TWO 110.6KB halves (27 features each) via
// linear global_load_lds; each segment's feature loop is barrier-free ds_read+MFMA.
// Restage protocol between segments: lgkmcnt(0) -> bar -> stage -> vmcnt(0) -> bar.
__global__ __launch_bounds__(512, 2) void poly2d_mfma(
    const float* __restrict__ x, const _Float16* __restrict__ fprep,
    const float* __restrict__ fconst, float* __restrict__ out)
{
    __shared__ __align__(16) char smB[HSLAB];   // 27 feature slots x 4096 B
    __shared__ __align__(16) char smx[32768];   // x tile [4][64][8cg swz][16B]; reused as os[128][33] f32

    const int t = threadIdx.x;
    const int lane = t & 63;
    const int wid = t >> 6;            // 0..7
    const int d = (blockIdx.x & 7) * 64 + (blockIdx.x >> 3); // XCD-bijective (512%8==0)
    const int oh = d >> 8;             // o-half 0/1
    const int b = (d >> 5) & 7;
    const int rp = d & 31;             // output rows rp*2, rp*2+1

    const char* slab = (const char*)fprep + (size_t)oh * OSLAB;

#define STAGEB(hs)                                                                        \
    do {                                                                                  \
        const char* s_ = slab + (size_t)(hs) * HSLAB;                                     \
        _Pragma("unroll")                                                                 \
        for (int r = 0; r < 13; ++r)                                                      \
            __builtin_amdgcn_global_load_lds(                                             \
                (const __attribute__((address_space(1))) unsigned int*)(const void*)(s_ + r * 8192 + t * 16), \
                (__attribute__((address_space(3))) unsigned int*)(void*)(smB + r * 8192 + (wid << 10)), \
                16, 0, 0);                                                                \
        if (wid < 4)                                                                      \
            __builtin_amdgcn_global_load_lds(                                             \
                (const __attribute__((address_space(1))) unsigned int*)(const void*)(s_ + 13 * 8192 + t * 16), \
                (__attribute__((address_space(3))) unsigned int*)(void*)(smB + 13 * 8192 + (wid << 10)), \
                16, 0, 0);                                                                \
    } while (0)

    STAGEB(0); // overlap with x staging below

    // ---- stage x tile (rows rp*2-1..rp*2+2, w 0..63, 64 c) swizzled fp16 ----
    {
        const int w = t & 63;
        #pragma unroll
        for (int h = 0; h < 4; ++h) {
            int h_in = rp * 2 - 1 + h;
            bool hok = ((unsigned)h_in < HH);
            #pragma unroll
            for (int cc = 0; cc < 2; ++cc) {
                int c = wid * 8 + cc * 4;  // channels c..c+3
                float v0 = 0.f, v1 = 0.f, v2 = 0.f, v3 = 0.f;
                if (hok) {
                    const float* gx = x + (((size_t)b * PIN + c) * HH + h_in) * WW + w;
                    v0 = gx[0]; v1 = gx[4096]; v2 = gx[8192]; v3 = gx[12288];
                }
                half4 pk = {(_Float16)v0, (_Float16)v1, (_Float16)v2, (_Float16)v3};
                int byte = ((h * 64 + w) * 8 + (wid ^ (w & 7))) * 16 + (c & 7) * 2;
                *(half4*)(smx + byte) = pk;
            }
        }
    }
    __syncthreads(); // drains gload_lds(seg0) + x ds_writes

    const int mtile = wid >> 1;        // 0..3: row j = mtile>>1, w-half wh = mtile&1
    const int kch = wid & 1;
    const int j = mtile >> 1;
    const int wh = mtile & 1;
    const int l31 = lane & 31;
    const int lhi = lane >> 5;

    // ---- load 9 shift panels x 2 kcq (A-frag: m=lane&31 -> w-pixel, k=lhi*8+elem) ----
    half8 xp[9][2];
    #pragma unroll
    for (int p = 1; p <= 9; ++p) {
        const int dh = (p - 1) / 3 - 1, dw = (p - 1) % 3 - 1;
        #pragma unroll
        for (int q = 0; q < 2; ++q) {
            int wl = wh * 32 + l31 + dw;          // -1..64
            int wc = wl < 0 ? 0 : (wl > 63 ? 63 : wl);
            int hidx = j + dh + 1;                // 0..3
            int cgl = (kch * 2 + q) * 2 + lhi;    // 0..7
            int byte = ((hidx * 64 + wc) * 8 + (cgl ^ (wc & 7))) * 16;
            half8 v = *(const half8*)(smx + byte);
            if ((unsigned)wl >= 64u) v = half8{}; // w out of image -> 0
            xp[p - 1][q] = v;
        }
    }
    __syncthreads(); // xp reads retired before smx becomes os

    f32x16 acc = {};
    const char* bwave = smB + (kch << 11) + (lane << 4); // + slot*4096 + q*1024

    // ---- segment runner: 27 feature-slots, barrier-free, depth-3 reg ring ----
    auto run_seg = [&](const int fb) {
        half8 Bb[3][2];
        #pragma unroll
        for (int s = 0; s < 2; ++s) {
            Bb[s][0] = *(const half8*)(bwave + s * 4096);
            Bb[s][1] = *(const half8*)(bwave + s * 4096 + 1024);
        }
        #pragma unroll
        for (int i = 0; i < 27; ++i) {
            if (i + 2 < 27) {
                Bb[(i + 2) % 3][0] = *(const half8*)(bwave + (i + 2) * 4096);
                Bb[(i + 2) % 3][1] = *(const half8*)(bwave + (i + 2) * 4096 + 1024);
            }
            const int f = fb + i;
            const int k = KT[f], l = LT[f];
            #pragma unroll
            for (int q = 0; q < 2; ++q) {
                half8 a = (k == 0) ? xp[l - 1][q] : xp[k - 1][q] * xp[l - 1][q];
                acc = __builtin_amdgcn_mfma_f32_32x32x16_f16(a, Bb[i % 3][q], acc, 0, 0, 0);
            }
        }
    };

    run_seg(0);

    // ---- restage slab half 1 (features 27..53) with full drain protocol ----
    asm volatile("s_waitcnt lgkmcnt(0)" ::: "memory"); // my ds_reads of seg0 retired
    __builtin_amdgcn_s_barrier();                      // everyone's reads retired
    asm volatile("" ::: "memory");
    STAGEB(1);
    asm volatile("s_waitcnt vmcnt(0)" ::: "memory");   // new slab landed
    __builtin_amdgcn_s_barrier();
    asm volatile("" ::: "memory");

    run_seg(27);
#undef STAGEB

    // ---- epilogue: reduce 2 kc-halves through LDS (smx reused as os[128][33]) ----
    float* os = (float*)smx;
    // C/D: col=lane&31 -> o_local, m=(r&3)+8*(r>>2)+4*lhi
    if (kch == 0) {
        #pragma unroll
        for (int r = 0; r < 16; ++r) {
            int m = (r & 3) + 8 * (r >> 2) + 4 * lhi;
            os[(mtile * 32 + m) * 33 + l31] = acc[r];
        }
    }
    __syncthreads();
    if (kch == 1) {
        #pragma unroll
        for (int r = 0; r < 16; ++r) {
            int m = (r & 3) + 8 * (r >> 2) + 4 * lhi;
            os[(mtile * 32 + m) * 33 + l31] += acc[r];
        }
    }
    __syncthreads();

    { // coalesced store: lanes sweep w; block covers o = oh*32 .. +31
        const int w = t & 63;
        #pragma unroll
        for (int h2 = 0; h2 < 2; ++h2) {
            #pragma unroll
            for (int oo = 0; oo < 4; ++oo) {
                int ol = wid * 4 + oo;
                float val = os[(h2 * 64 + w) * 33 + ol] + fconst[oh * 32 + ol];
                out[(((size_t)b * POUT + (oh * 32 + ol)) * HH + (rp * 2 + h2)) * WW + w] = val;
            }
        }
    }
}

// ---------------- fp32 fallback, used only if ws too small ----------------
__global__ __launch_bounds__(256) void poly2d_fp32(
    const float* __restrict__ x, const float* __restrict__ f,
    const float* __restrict__ bias, float* __restrict__ out)
{
    const int t = threadIdx.x;
    const int wo = t & 63;
    const int ho = (blockIdx.x & 15) * 4 + (t >> 6);
    const int o = (blockIdx.x >> 4) & 63;
    const int b = blockIdx.x >> 10;

    float acc = bias[o];
    const float* xb = x + (size_t)b * PIN * HH * WW;
    const float* fo = f + (size_t)o * PIN * 100;
    for (int c = 0; c < PIN; ++c) {
        const float* xc = xb + (size_t)c * HH * WW;
        float s[10];
        s[0] = 1.0f;
        #pragma unroll
        for (int kh = 0; kh < 3; ++kh) {
            int h = ho - 1 + kh;
            bool hok = ((unsigned)h < HH);
            #pragma unroll
            for (int kw = 0; kw < 3; ++kw) {
                int w = wo - 1 + kw;
                s[1 + kh * 3 + kw] = (hok && (unsigned)w < WW) ? xc[h * WW + w] : 0.0f;
            }
        }
        const float* fc = fo + c * 100;
        #pragma unroll
        for (int i = 0; i < 10; ++i) {
            float wsum = 0.0f;
            #pragma unroll
            for (int j = 0; j < 10; ++j) wsum = fmaf(fc[i * 10 + j], s[j], wsum);
            acc = fmaf(wsum, s[i], acc);
        }
    }
    out[(((size_t)b * POUT + o) * HH + ho) * WW + wo] = acc;
}

extern "C" void kernel_launch(void* const* d_in, const int* in_sizes, int n_in,
                              void* d_out, int out_size, void* d_ws, size_t ws_size,
                              hipStream_t stream) {
    const float* x    = (const float*)d_in[0];
    const float* filt = (const float*)d_in[1];
    const float* bias = (const float*)d_in[2];
    float* out = (float*)d_out;

    const size_t FPREP_BYTES = 2 * (size_t)OSLAB; // 442368
    if (ws_size < FPREP_BYTES + 256) {
        poly2d_fp32<<<dim3(8 * 64 * 16), dim3(256), 0, stream>>>(x, filt, bias, out);
        return;
    }
    _Float16* fprep = (_Float16*)d_ws;
    float* fconst = (float*)((char*)d_ws + FPREP_BYTES);

    prep_filters<<<dim3(109), dim3(256), 0, stream>>>(filt, bias, fprep, fconst);
    poly2d_mfma<<<dim3(512), dim3(512), 0, stream>>>(x, fprep, fconst, out);
}

// Round 14
// 29.836 us; speedup vs baseline: 4.3088x; 4.3088x over previous
//
#include <hip/hip_runtime.h>
#include <stdint.h>

#define HH 64
#define WW 64
#define PIN 64
#define POUT 64
#define NFEAT 54

typedef _Float16 half8 __attribute__((ext_vector_type(8)));
typedef _Float16 half4 __attribute__((ext_vector_type(4)));
typedef float f32x4 __attribute__((ext_vector_type(4)));
typedef float f32x16 __attribute__((ext_vector_type(16)));

// feature enumeration tables: f -> (k,l). constexpr (NOT __constant__) so that
// fully-unrolled loops fold KT[f]/LT[f] to literals -> xp[] indices are static
// -> xp stays in VGPRs (rule #20; r13 post-mortem: __constant__ tables caused
// runtime indexing -> LDS-rematerialization/scratch-spill since round 7).
__device__ constexpr int KT[54] = {0,0,0,0,0,0,0,0,0, 1,1,1,1,1,1,1,1,1, 2,2,2,2,2,2,2,2,
                                   3,3,3,3,3,3,3, 4,4,4,4,4,4, 5,5,5,5,5, 6,6,6,6, 7,7,7, 8,8, 9};
__device__ constexpr int LT[54] = {1,2,3,4,5,6,7,8,9, 1,2,3,4,5,6,7,8,9, 2,3,4,5,6,7,8,9,
                                   3,4,5,6,7,8,9, 4,5,6,7,8,9, 5,6,7,8,9, 6,7,8,9, 7,8,9, 8,9, 9};

// ---------------- filter prep ----------------
// Fprep in FRAGMENT order: byte(f,o,c) = f*8192 + (c>>4)*2048 + (o>>5)*1024
//   + ((o&31)+32*((c>>3)&1))*16 + (c&7)*2
// so a wave (kc quarter) reads b0 at f*8192+kc*2048+lane*16 (1KB contiguous), b1 at +1024.
__global__ void prep_filters(const float* __restrict__ f, const float* __restrict__ bias,
                             _Float16* __restrict__ fprep, float* __restrict__ fconst) {
    if (blockIdx.x == 108) {
        int o = threadIdx.x;
        if (o < POUT) {
            float s = bias[o];
            for (int c = 0; c < PIN; ++c) s += f[(size_t)(o * PIN + c) * 100];
            fconst[o] = s;
        }
        return;
    }
    int tid = blockIdx.x * 256 + threadIdx.x;   // 0..27647 = 54*64*8
    int feat = tid >> 9;
    int rem = tid & 511;
    int o = rem >> 3;
    int cg = rem & 7;                           // c = cg*8 + jj
    int k = KT[feat], l = LT[feat];

    half8 chunk;
    #pragma unroll
    for (int jj = 0; jj < 8; ++jj) {
        int c = cg * 8 + jj;
        const float* fc = f + (size_t)(o * PIN + c) * 100;
        float v;
        if (k == 0)      v = fc[l] + fc[l * 10];
        else if (k == l) v = fc[k * 10 + k];
        else             v = fc[k * 10 + l] + fc[l * 10 + k];
        chunk[jj] = (_Float16)v;
    }
    int lane = (o & 31) + 32 * (cg & 1);
    size_t byte = (size_t)feat * 8192 + (cg >> 1) * 2048 + (o >> 5) * 1024 + lane * 16;
    *(half8*)((char*)fprep + byte) = chunk;
}

// ---------------- main MFMA kernel ----------------
// Round-10 structure (A/B test vs r10: only KT/LT constexpr + ring depth 3).
// grid 512 = b(8) x hrow(64), XCD-swizzled; block 512 thr = 8 waves =
// 2 m-tiles (32 px) x 4 kc-quarters (K=16). MFMA 32x32x16_f16.
// Barrier-free main loop: each wave streams its B fragments from global
// (fragment-ordered, fully coalesced) through a depth-3 register ring.
__global__ __launch_bounds__(512, 4) void poly2d_mfma(
    const float* __restrict__ x, const _Float16* __restrict__ fprep,
    const float* __restrict__ fconst, float* __restrict__ out)
{
    __shared__ __align__(16) char smx[25344];  // x tile [3][66][8cg swz][16B]; reused as os[64][65] f32

    const int t = threadIdx.x;
    const int lane = t & 63;
    const int wid = t >> 6;            // 0..7
    // XCD-bijective swizzle (512 % 8 == 0)
    const int bid = (blockIdx.x & 7) * 64 + (blockIdx.x >> 3);
    const int b = bid >> 6;
    const int hrow = bid & 63;

    // ---- stage x tile (rows hrow-1..hrow+1, wl 0..65, 64 c) as swizzled fp16 ----
    {
        const int w = t & 63;
        const int wl = w + 1;
        #pragma unroll
        for (int h = 0; h < 3; ++h) {
            int h_in = hrow - 1 + h;
            bool hok = ((unsigned)h_in < HH);
            #pragma unroll
            for (int cc = 0; cc < 2; ++cc) {
                int c = wid * 8 + cc * 4;  // channels c..c+3
                float v0 = 0.f, v1 = 0.f, v2 = 0.f, v3 = 0.f;
                if (hok) {
                    const float* gx = x + (((size_t)b * PIN + c) * HH + h_in) * WW + w;
                    v0 = gx[0]; v1 = gx[4096]; v2 = gx[8192]; v3 = gx[12288];
                }
                half4 pk = {(_Float16)v0, (_Float16)v1, (_Float16)v2, (_Float16)v3};
                int byte = ((h * 66 + wl) * 8 + ((c >> 3) ^ (wl & 7))) * 16 + (c & 7) * 2;
                *(half4*)(smx + byte) = pk;
            }
        }
        if (t < 48) { // w halo: wl=0 and wl=65 out of image -> zero
            int h = t >> 4, side = (t >> 3) & 1, cg = t & 7;
            int wl2 = side ? 65 : 0;
            int byte = ((h * 66 + wl2) * 8 + (cg ^ (wl2 & 7))) * 16;
            f32x4 z = {0.f, 0.f, 0.f, 0.f};
            *(f32x4*)(smx + byte) = z;
        }
    }
    __syncthreads();

    const int kc = wid >> 1;           // 0..3 channel quarter
    const int mwid = wid & 1;          // m-tile (w-half)
    const int wbase = mwid * 32;
    const int l31 = lane & 31;
    const int lhi = lane >> 5;         // 0/1

    // ---- load 9 shift panels (A-frag: row=lane&31 -> pixel, k=(lane>>5)*8+j) ----
    half8 xp[9];
    #pragma unroll
    for (int p = 1; p <= 9; ++p) {
        const int dh = (p - 1) / 3 - 1, dw = (p - 1) % 3 - 1;
        int wl = wbase + l31 + dw + 1;
        int hidx = dh + 1;
        int cgl = kc * 2 + lhi;
        int byte = ((hidx * 66 + wl) * 8 + (cgl ^ (wl & 7))) * 16;
        xp[p - 1] = *(const half8*)(smx + byte);
    }
    __syncthreads(); // all xp reads done before the os-write epilogue may start

    // ---- barrier-free streaming loop: coalesced B frags, depth-3 reg ring ----
    // fragment order: b0 @ f*8192 + kc*2048 + lane*16 ; b1 @ +1024
    const char* fbase = (const char*)fprep + (kc << 11) + (lane << 4);

    half8 Bb[3][2];
    #pragma unroll
    for (int s = 0; s < 2; ++s) {
        Bb[s][0] = *(const half8*)(fbase + (size_t)s * 8192);
        Bb[s][1] = *(const half8*)(fbase + (size_t)s * 8192 + 1024);
    }

    f32x16 acc0 = {}, acc1 = {};

    #pragma unroll
    for (int f = 0; f < NFEAT; ++f) {
        if (f + 2 < NFEAT) {
            Bb[(f + 2) % 3][0] = *(const half8*)(fbase + (size_t)(f + 2) * 8192);
            Bb[(f + 2) % 3][1] = *(const half8*)(fbase + (size_t)(f + 2) * 8192 + 1024);
        }
        constexpr_loop_body: ;
        const int k = KT[f], l = LT[f];   // f is unroll-constant -> folds to literals
        half8 a = (k == 0) ? xp[l - 1] : xp[k - 1] * xp[l - 1];
        acc0 = __builtin_amdgcn_mfma_f32_32x32x16_f16(a, Bb[f % 3][0], acc0, 0, 0, 0);
        acc1 = __builtin_amdgcn_mfma_f32_32x32x16_f16(a, Bb[f % 3][1], acc1, 0, 0, 0);
    }

    __syncthreads(); // loop done; x-region free for output staging
    float* os = (float*)smx; // [64 px][65]

    // reduce 4 kc partials (C/D: col=lane&31 (+nb*32), row=(r&3)+8*(r>>2)+4*lhi)
    #pragma unroll
    for (int pass = 0; pass < 4; ++pass) {
        if (kc == pass) {
            #pragma unroll
            for (int nb = 0; nb < 2; ++nb) {
                #pragma unroll
                for (int r = 0; r < 16; ++r) {
                    int row = (r & 3) + 8 * (r >> 2) + 4 * lhi;
                    int m = mwid * 32 + row;
                    int col = l31 + nb * 32;
                    float v = nb ? acc1[r] : acc0[r];
                    if (pass == 0) os[m * 65 + col] = v;
                    else           os[m * 65 + col] += v;
                }
            }
        }
        __syncthreads();
    }

    { // coalesced store: lanes sweep w
        const int w = t & 63;
        #pragma unroll
        for (int oo = 0; oo < 8; ++oo) {
            int o = wid * 8 + oo;
            float val = os[w * 65 + o] + fconst[o];
            out[(((size_t)b * POUT + o) * HH + hrow) * WW + w] = val;
        }
    }
}

// ---------------- fp32 fallback, used only if ws too small ----------------
__global__ __launch_bounds__(256) void poly2d_fp32(
    const float* __restrict__ x, const float* __restrict__ f,
    const float* __restrict__ bias, float* __restrict__ out)
{
    const int t = threadIdx.x;
    const int wo = t & 63;
    const int ho = (blockIdx.x & 15) * 4 + (t >> 6);
    const int o = (blockIdx.x >> 4) & 63;
    const int b = blockIdx.x >> 10;

    float acc = bias[o];
    const float* xb = x + (size_t)b * PIN * HH * WW;
    const float* fo = f + (size_t)o * PIN * 100;
    for (int c = 0; c < PIN; ++c) {
        const float* xc = xb + (size_t)c * HH * WW;
        float s[10];
        s[0] = 1.0f;
        #pragma unroll
        for (int kh = 0; kh < 3; ++kh) {
            int h = ho - 1 + kh;
            bool hok = ((unsigned)h < HH);
            #pragma unroll
            for (int kw = 0; kw < 3; ++kw) {
                int w = wo - 1 + kw;
                s[1 + kh * 3 + kw] = (hok && (unsigned)w < WW) ? xc[h * WW + w] : 0.0f;
            }
        }
        const float* fc = fo + c * 100;
        #pragma unroll
        for (int i = 0; i < 10; ++i) {
            float wsum = 0.0f;
            #pragma unroll
            for (int j = 0; j < 10; ++j) wsum = fmaf(fc[i * 10 + j], s[j], wsum);
            acc = fmaf(wsum, s[i], acc);
        }
    }
    out[(((size_t)b * POUT + o) * HH + ho) * WW + wo] = acc;
}

extern "C" void kernel_launch(void* const* d_in, const int* in_sizes, int n_in,
                              void* d_out, int out_size, void* d_ws, size_t ws_size,
                              hipStream_t stream) {
    const float* x    = (const float*)d_in[0];
    const float* filt = (const float*)d_in[1];
    const float* bias = (const float*)d_in[2];
    float* out = (float*)d_out;

    const size_t FPREP_BYTES = (size_t)NFEAT * POUT * PIN * 2; // 442368
    if (ws_size < FPREP_BYTES + 256) {
        poly2d_fp32<<<dim3(8 * 64 * 16), dim3(256), 0, stream>>>(x, filt, bias, out);
        return;
    }
    _Float16* fprep = (_Float16*)d_ws;
    float* fconst = (float*)((char*)d_ws + FPREP_BYTES);

    prep_filters<<<dim3(109), dim3(256), 0, stream>>>(filt, bias, fprep, fconst);
    poly2d_mfma<<<dim3(512), dim3(512), 0, stream>>>(x, fprep, fconst, out);
}

// Round 15
// 29.323 us; speedup vs baseline: 4.3841x; 1.0175x over previous
//
#include <hip/hip_runtime.h>
#include <stdint.h>

#define HH 64
#define WW 64
#define PIN 64
#define POUT 64
#define NFEAT 54
#define OSLAB 221184   // bytes per o-half: 54 feat * 4096 (32 o x 64 c fp16)
#define HSLAB 110592   // half slab: 27 features * 4096

typedef _Float16 half8 __attribute__((ext_vector_type(8)));
typedef _Float16 half4 __attribute__((ext_vector_type(4)));
typedef float f32x4 __attribute__((ext_vector_type(4)));
typedef float f32x16 __attribute__((ext_vector_type(16)));

// constexpr (NOT __constant__) + literal indices after unroll -> folds to
// immediates -> xp[] statically indexed -> stays in VGPRs (rule #20).
__device__ constexpr int KT[54] = {0,0,0,0,0,0,0,0,0, 1,1,1,1,1,1,1,1,1, 2,2,2,2,2,2,2,2,
                                   3,3,3,3,3,3,3, 4,4,4,4,4,4, 5,5,5,5,5, 6,6,6,6, 7,7,7, 8,8, 9};
__device__ constexpr int LT[54] = {1,2,3,4,5,6,7,8,9, 1,2,3,4,5,6,7,8,9, 2,3,4,5,6,7,8,9,
                                   3,4,5,6,7,8,9, 4,5,6,7,8,9, 5,6,7,8,9, 6,7,8,9, 7,8,9, 8,9, 9};

// ---------------- filter prep ----------------
// Fragment-order, o-half-major:
//   byte(f,o,c) = (o>>5)*OSLAB + f*4096 + (c>>4)*1024 + ((o&31)+32*((c>>3)&1))*16 + (c&7)*2
// One feature = 4096 B (4 kcq x 64 lanes x 16 B). Wave (kc-half kch) reads frag q of
// feature-slot i at smB + i*4096 + (kch*2+q)*1024 + lane*16.
__global__ void prep_filters(const float* __restrict__ f, const float* __restrict__ bias,
                             _Float16* __restrict__ fprep, float* __restrict__ fconst) {
    if (blockIdx.x == 108) {
        int o = threadIdx.x;
        if (o < POUT) {
            float s = bias[o];
            for (int c = 0; c < PIN; ++c) s += f[(size_t)(o * PIN + c) * 100];
            fconst[o] = s;
        }
        return;
    }
    int tid = blockIdx.x * 256 + threadIdx.x;   // 0..27647 = 54*64*8
    int feat = tid >> 9;
    int rem = tid & 511;
    int o = rem >> 3;
    int cg = rem & 7;                           // c = cg*8 + jj
    int k = KT[feat], l = LT[feat];

    half8 chunk;
    #pragma unroll
    for (int jj = 0; jj < 8; ++jj) {
        int c = cg * 8 + jj;
        const float* fc = f + (size_t)(o * PIN + c) * 100;
        float v;
        if (k == 0)      v = fc[l] + fc[l * 10];
        else if (k == l) v = fc[k * 10 + k];
        else             v = fc[k * 10 + l] + fc[l * 10 + k];
        chunk[jj] = (_Float16)v;
    }
    size_t byte = (size_t)(o >> 5) * OSLAB + (size_t)feat * 4096 + (cg >> 1) * 1024
                + ((o & 31) + 32 * (cg & 1)) * 16;
    *(half8*)((char*)fprep + byte) = chunk;
}

// ---------------- main MFMA kernel ----------------
// r13 structure, spill-free: grid 512 = oh(2) x b(8) x rowpair(32), XCD-swizzled;
// block 512 thr = 8 waves = 4 m-tiles (32 px: row j x w-half) x 2 kc-halves (K=32).
// B: one o-half slab (221KB) staged in TWO 110.6KB halves via linear global_load_lds;
// each segment's 27-feature loop is barrier-free ds_read_b128 + MFMA with LITERAL
// feature indices (macro base). Restage: lgkmcnt(0) -> bar -> stage -> vmcnt(0) -> bar.
__global__ __launch_bounds__(512, 2) void poly2d_mfma(
    const float* __restrict__ x, const _Float16* __restrict__ fprep,
    const float* __restrict__ fconst, float* __restrict__ out)
{
    __shared__ __align__(16) char smB[HSLAB];   // 27 feature slots x 4096 B
    __shared__ __align__(16) char smx[32768];   // x tile [4][64][8cg swz][16B]; reused as os[128][33] f32

    const int t = threadIdx.x;
    const int lane = t & 63;
    const int wid = t >> 6;            // 0..7
    const int d = (blockIdx.x & 7) * 64 + (blockIdx.x >> 3); // XCD-bijective (512%8==0)
    const int oh = d >> 8;             // o-half 0/1
    const int b = (d >> 5) & 7;
    const int rp = d & 31;             // output rows rp*2, rp*2+1

    const char* slab = (const char*)fprep + (size_t)oh * OSLAB;

#define STAGEB(hs)                                                                        \
    do {                                                                                  \
        const char* s_ = slab + (size_t)(hs) * HSLAB;                                     \
        _Pragma("unroll")                                                                 \
        for (int r = 0; r < 13; ++r)                                                      \
            __builtin_amdgcn_global_load_lds(                                             \
                (const __attribute__((address_space(1))) unsigned int*)(const void*)(s_ + r * 8192 + t * 16), \
                (__attribute__((address_space(3))) unsigned int*)(void*)(smB + r * 8192 + (wid << 10)), \
                16, 0, 0);                                                                \
        if (wid < 4)                                                                      \
            __builtin_amdgcn_global_load_lds(                                             \
                (const __attribute__((address_space(1))) unsigned int*)(const void*)(s_ + 13 * 8192 + t * 16), \
                (__attribute__((address_space(3))) unsigned int*)(void*)(smB + 13 * 8192 + (wid << 10)), \
                16, 0, 0);                                                                \
    } while (0)

    STAGEB(0); // overlaps with x staging below; __syncthreads drains both

    // ---- stage x tile (rows rp*2-1..rp*2+2, w 0..63, 64 c) swizzled fp16 ----
    {
        const int w = t & 63;
        #pragma unroll
        for (int h = 0; h < 4; ++h) {
            int h_in = rp * 2 - 1 + h;
            bool hok = ((unsigned)h_in < HH);
            #pragma unroll
            for (int cc = 0; cc < 2; ++cc) {
                int c = wid * 8 + cc * 4;  // channels c..c+3
                float v0 = 0.f, v1 = 0.f, v2 = 0.f, v3 = 0.f;
                if (hok) {
                    const float* gx = x + (((size_t)b * PIN + c) * HH + h_in) * WW + w;
                    v0 = gx[0]; v1 = gx[4096]; v2 = gx[8192]; v3 = gx[12288];
                }
                half4 pk = {(_Float16)v0, (_Float16)v1, (_Float16)v2, (_Float16)v3};
                int byte = ((h * 64 + w) * 8 + (wid ^ (w & 7))) * 16 + (c & 7) * 2;
                *(half4*)(smx + byte) = pk;
            }
        }
    }
    __syncthreads(); // drains gload_lds(seg0) + x ds_writes

    const int mtile = wid >> 1;        // 0..3: row j = mtile>>1, w-half wh = mtile&1
    const int kch = wid & 1;
    const int j = mtile >> 1;
    const int wh = mtile & 1;
    const int l31 = lane & 31;
    const int lhi = lane >> 5;

    // ---- load 9 shift panels x 2 kcq (A-frag: m=lane&31 -> w-pixel, k=lhi*8+elem) ----
    half8 xp[9][2];
    #pragma unroll
    for (int p = 1; p <= 9; ++p) {
        const int dh = (p - 1) / 3 - 1, dw = (p - 1) % 3 - 1;
        #pragma unroll
        for (int q = 0; q < 2; ++q) {
            int wl = wh * 32 + l31 + dw;          // -1..64
            int wc = wl < 0 ? 0 : (wl > 63 ? 63 : wl);
            int hidx = j + dh + 1;                // 0..3
            int cgl = (kch * 2 + q) * 2 + lhi;    // 0..7
            int byte = ((hidx * 64 + wc) * 8 + (cgl ^ (wc & 7))) * 16;
            half8 v = *(const half8*)(smx + byte);
            if ((unsigned)wl >= 64u) v = half8{}; // w out of image -> 0
            xp[p - 1][q] = v;
        }
    }
    __syncthreads(); // xp reads retired before smx becomes os

    f32x16 acc = {};
    const char* bwave = smB + (kch << 11) + (lane << 4); // + slot*4096 + q*1024

    // ---- segment: 27 feature-slots, barrier-free, depth-3 reg ring, LITERAL base ----
#define RUN_SEG(FB)                                                                       \
    do {                                                                                  \
        half8 Bb[3][2];                                                                   \
        _Pragma("unroll")                                                                 \
        for (int s = 0; s < 2; ++s) {                                                     \
            Bb[s][0] = *(const half8*)(bwave + s * 4096);                                 \
            Bb[s][1] = *(const half8*)(bwave + s * 4096 + 1024);                          \
        }                                                                                 \
        _Pragma("unroll")                                                                 \
        for (int i = 0; i < 27; ++i) {                                                    \
            if (i + 2 < 27) {                                                             \
                Bb[(i + 2) % 3][0] = *(const half8*)(bwave + (i + 2) * 4096);             \
                Bb[(i + 2) % 3][1] = *(const half8*)(bwave + (i + 2) * 4096 + 1024);      \
            }                                                                             \
            const int k_ = KT[(FB) + i], l_ = LT[(FB) + i]; /* literal after unroll */    \
            _Pragma("unroll")                                                             \
            for (int q = 0; q < 2; ++q) {                                                 \
                half8 a_ = (k_ == 0) ? xp[l_ - 1][q] : xp[k_ - 1][q] * xp[l_ - 1][q];     \
                acc = __builtin_amdgcn_mfma_f32_32x32x16_f16(a_, Bb[i % 3][q], acc, 0, 0, 0); \
            }                                                                             \
        }                                                                                 \
    } while (0)

    RUN_SEG(0);

    // ---- restage slab half 1 (features 27..53) with full drain protocol ----
    asm volatile("s_waitcnt lgkmcnt(0)" ::: "memory"); // my ds_reads of seg0 retired
    __builtin_amdgcn_s_barrier();                      // everyone's reads retired
    asm volatile("" ::: "memory");
    STAGEB(1);
    asm volatile("s_waitcnt vmcnt(0)" ::: "memory");   // new slab landed
    __builtin_amdgcn_s_barrier();
    asm volatile("" ::: "memory");

    RUN_SEG(27);
#undef RUN_SEG
#undef STAGEB

    // ---- epilogue: reduce 2 kc-halves through LDS (smx reused as os[128][33]) ----
    float* os = (float*)smx;
    // C/D: col=lane&31 -> o_local, m=(r&3)+8*(r>>2)+4*lhi
    if (kch == 0) {
        #pragma unroll
        for (int r = 0; r < 16; ++r) {
            int m = (r & 3) + 8 * (r >> 2) + 4 * lhi;
            os[(mtile * 32 + m) * 33 + l31] = acc[r];
        }
    }
    __syncthreads();
    if (kch == 1) {
        #pragma unroll
        for (int r = 0; r < 16; ++r) {
            int m = (r & 3) + 8 * (r >> 2) + 4 * lhi;
            os[(mtile * 32 + m) * 33 + l31] += acc[r];
        }
    }
    __syncthreads();

    { // coalesced store: lanes sweep w; block covers o = oh*32 .. +31
        const int w = t & 63;
        #pragma unroll
        for (int h2 = 0; h2 < 2; ++h2) {
            #pragma unroll
            for (int oo = 0; oo < 4; ++oo) {
                int ol = wid * 4 + oo;
                float val = os[(h2 * 64 + w) * 33 + ol] + fconst[oh * 32 + ol];
                out[(((size_t)b * POUT + (oh * 32 + ol)) * HH + (rp * 2 + h2)) * WW + w] = val;
            }
        }
    }
}

// ---------------- fp32 fallback, used only if ws too small ----------------
__global__ __launch_bounds__(256) void poly2d_fp32(
    const float* __restrict__ x, const float* __restrict__ f,
    const float* __restrict__ bias, float* __restrict__ out)
{
    const int t = threadIdx.x;
    const int wo = t & 63;
    const int ho = (blockIdx.x & 15) * 4 + (t >> 6);
    const int o = (blockIdx.x >> 4) & 63;
    const int b = blockIdx.x >> 10;

    float acc = bias[o];
    const float* xb = x + (size_t)b * PIN * HH * WW;
    const float* fo = f + (size_t)o * PIN * 100;
    for (int c = 0; c < PIN; ++c) {
        const float* xc = xb + (size_t)c * HH * WW;
        float s[10];
        s[0] = 1.0f;
        #pragma unroll
        for (int kh = 0; kh < 3; ++kh) {
            int h = ho - 1 + kh;
            bool hok = ((unsigned)h < HH);
            #pragma unroll
            for (int kw = 0; kw < 3; ++kw) {
                int w = wo - 1 + kw;
                s[1 + kh * 3 + kw] = (hok && (unsigned)w < WW) ? xc[h * WW + w] : 0.0f;
            }
        }
        const float* fc = fo + c * 100;
        #pragma unroll
        for (int i = 0; i < 10; ++i) {
            float wsum = 0.0f;
            #pragma unroll
            for (int j = 0; j < 10; ++j) wsum = fmaf(fc[i * 10 + j], s[j], wsum);
            acc = fmaf(wsum, s[i], acc);
        }
    }
    out[(((size_t)b * POUT + o) * HH + ho) * WW + wo] = acc;
}

extern "C" void kernel_launch(void* const* d_in, const int* in_sizes, int n_in,
                              void* d_out, int out_size, void* d_ws, size_t ws_size,
                              hipStream_t stream) {
    const float* x    = (const float*)d_in[0];
    const float* filt = (const float*)d_in[1];
    const float* bias = (const float*)d_in[2];
    float* out = (float*)d_out;

    const size_t FPREP_BYTES = 2 * (size_t)OSLAB; // 442368
    if (ws_size < FPREP_BYTES + 256) {
        poly2d_fp32<<<dim3(8 * 64 * 16), dim3(256), 0, stream>>>(x, filt, bias, out);
        return;
    }
    _Float16* fprep = (_Float16*)d_ws;
    float* fconst = (float*)((char*)d_ws + FPREP_BYTES);

    prep_filters<<<dim3(109), dim3(256), 0, stream>>>(filt, bias, fprep, fconst);
    poly2d_mfma<<<dim3(512), dim3(512), 0, stream>>>(x, fprep, fconst, out);
}

// Round 16
// 29.230 us; speedup vs baseline: 4.3981x; 1.0032x over previous
//
#include <hip/hip_runtime.h>
#include <stdint.h>

#define HH 64
#define WW 64
#define PIN 64
#define POUT 64
#define NFEAT 54
#define SEGB 24576     // 3 features x 8192 B per segment
#define NSEG 18

typedef _Float16 half8 __attribute__((ext_vector_type(8)));
typedef _Float16 half4 __attribute__((ext_vector_type(4)));
typedef float f32x4 __attribute__((ext_vector_type(4)));
typedef float f32x16 __attribute__((ext_vector_type(16)));

// constexpr (NOT __constant__): folds to literals under full unroll -> xp[]
// statically indexed -> stays in VGPRs (rule #20, r13 lesson).
__device__ constexpr int KT[54] = {0,0,0,0,0,0,0,0,0, 1,1,1,1,1,1,1,1,1, 2,2,2,2,2,2,2,2,
                                   3,3,3,3,3,3,3, 4,4,4,4,4,4, 5,5,5,5,5, 6,6,6,6, 7,7,7, 8,8, 9};
__device__ constexpr int LT[54] = {1,2,3,4,5,6,7,8,9, 1,2,3,4,5,6,7,8,9, 2,3,4,5,6,7,8,9,
                                   3,4,5,6,7,8,9, 4,5,6,7,8,9, 5,6,7,8,9, 6,7,8,9, 7,8,9, 8,9, 9};

// ---------------- filter prep (r10/r14 verified layout) ----------------
// Fragment order: byte(f,o,c) = f*8192 + (c>>4)*2048 + (o>>5)*1024
//   + ((o&31)+32*((c>>3)&1))*16 + (c&7)*2
// Wave (kc quarter) reads b0 at f*8192 + kc*2048 + lane*16, b1 at +1024.
__global__ void prep_filters(const float* __restrict__ f, const float* __restrict__ bias,
                             _Float16* __restrict__ fprep, float* __restrict__ fconst) {
    if (blockIdx.x == 108) {
        int o = threadIdx.x;
        if (o < POUT) {
            float s = bias[o];
            for (int c = 0; c < PIN; ++c) s += f[(size_t)(o * PIN + c) * 100];
            fconst[o] = s;
        }
        return;
    }
    int tid = blockIdx.x * 256 + threadIdx.x;   // 0..27647 = 54*64*8
    int feat = tid >> 9;
    int rem = tid & 511;
    int o = rem >> 3;
    int cg = rem & 7;                           // c = cg*8 + jj
    int k = KT[feat], l = LT[feat];

    half8 chunk;
    #pragma unroll
    for (int jj = 0; jj < 8; ++jj) {
        int c = cg * 8 + jj;
        const float* fc = f + (size_t)(o * PIN + c) * 100;
        float v;
        if (k == 0)      v = fc[l] + fc[l * 10];
        else if (k == l) v = fc[k * 10 + k];
        else             v = fc[k * 10 + l] + fc[l * 10 + k];
        chunk[jj] = (_Float16)v;
    }
    int lane = (o & 31) + 32 * (cg & 1);
    size_t byte = (size_t)feat * 8192 + (cg >> 1) * 2048 + (o >> 5) * 1024 + lane * 16;
    *(half8*)((char*)fprep + byte) = chunk;
}

// ---------------- main MFMA kernel ----------------
// r14 wave geometry (grid 512 = b(8) x hrow(64) XCD-swizzled; block 512 = 8 waves =
// 2 m-tiles x 4 kcq; MFMA 32x32x16_f16) with B via DOUBLE-BUFFERED LDS segments:
// 18 segments x 3 features (24KB), staged by linear global_load_lds, counted
// vmcnt(3) (T3/T4 - never drain to 0 in steady state). LDS 74.5KB -> 2 blocks/CU
// (16 waves) so phase barriers of one block overlap the other's compute.
__global__ __launch_bounds__(512, 4) void poly2d_mfma(
    const float* __restrict__ x, const _Float16* __restrict__ fprep,
    const float* __restrict__ fconst, float* __restrict__ out)
{
    __shared__ __align__(16) char smB[2 * SEGB];  // B dbuf: 2 x 3 feat x 8192
    __shared__ __align__(16) char smx[25344];     // x tile [3][66][8cg swz][16B]; reused as os[64][65] f32

    const int t = threadIdx.x;
    const int lane = t & 63;
    const int wid = t >> 6;            // 0..7
    // XCD-bijective swizzle (512 % 8 == 0)
    const int bid = (blockIdx.x & 7) * 64 + (blockIdx.x >> 3);
    const int b = bid >> 6;
    const int hrow = bid & 63;

#define STAGE(ss)                                                                         \
    do {                                                                                  \
        const char* s_ = (const char*)fprep + (size_t)(ss) * SEGB;                        \
        _Pragma("unroll")                                                                 \
        for (int r_ = 0; r_ < 3; ++r_)                                                    \
            __builtin_amdgcn_global_load_lds(                                             \
                (const __attribute__((address_space(1))) unsigned int*)(const void*)(s_ + r_ * 8192 + t * 16), \
                (__attribute__((address_space(3))) unsigned int*)(void*)(smB + ((ss) & 1) * SEGB + r_ * 8192 + (wid << 10)), \
                16, 0, 0);                                                                \
    } while (0)

    // prologue: stage segments 0,1 (6 loads/thread); first __syncthreads drains all
    STAGE(0);
    STAGE(1);

    // ---- stage x tile (rows hrow-1..hrow+1, wl 0..65, 64 c) as swizzled fp16 ----
    {
        const int w = t & 63;
        const int wl = w + 1;
        #pragma unroll
        for (int h = 0; h < 3; ++h) {
            int h_in = hrow - 1 + h;
            bool hok = ((unsigned)h_in < HH);
            #pragma unroll
            for (int cc = 0; cc < 2; ++cc) {
                int c = wid * 8 + cc * 4;  // channels c..c+3
                float v0 = 0.f, v1 = 0.f, v2 = 0.f, v3 = 0.f;
                if (hok) {
                    const float* gx = x + (((size_t)b * PIN + c) * HH + h_in) * WW + w;
                    v0 = gx[0]; v1 = gx[4096]; v2 = gx[8192]; v3 = gx[12288];
                }
                half4 pk = {(_Float16)v0, (_Float16)v1, (_Float16)v2, (_Float16)v3};
                int byte = ((h * 66 + wl) * 8 + ((c >> 3) ^ (wl & 7))) * 16 + (c & 7) * 2;
                *(half4*)(smx + byte) = pk;
            }
        }
        if (t < 48) { // w halo: wl=0 and wl=65 out of image -> zero
            int h = t >> 4, side = (t >> 3) & 1, cg = t & 7;
            int wl2 = side ? 65 : 0;
            int byte = ((h * 66 + wl2) * 8 + (cg ^ (wl2 & 7))) * 16;
            f32x4 z = {0.f, 0.f, 0.f, 0.f};
            *(f32x4*)(smx + byte) = z;
        }
    }
    __syncthreads(); // drains vmcnt(0)+lgkm: x tile ready, segments 0,1 landed

    const int kc = wid >> 1;           // 0..3 channel quarter
    const int mwid = wid & 1;          // m-tile (w-half)
    const int wbase = mwid * 32;
    const int l31 = lane & 31;
    const int lhi = lane >> 5;         // 0/1

    // ---- load 9 shift panels (A-frag: row=lane&31 -> pixel, k=(lane>>5)*8+j) ----
    half8 xp[9];
    #pragma unroll
    for (int p = 1; p <= 9; ++p) {
        const int dh = (p - 1) / 3 - 1, dw = (p - 1) % 3 - 1;
        int wl = wbase + l31 + dw + 1;
        int hidx = dh + 1;
        int cgl = kc * 2 + lhi;
        int byte = ((hidx * 66 + wl) * 8 + (cgl ^ (wl & 7))) * 16;
        xp[p - 1] = *(const half8*)(smx + byte);
    }
    __syncthreads(); // all xp reads done before the os-write epilogue may start

    f32x16 acc0 = {}, acc1 = {};

    // ---- 18 phases x 3 features: dbuf LDS B, counted vmcnt, 2 barriers/phase ----
    #pragma unroll
    for (int s = 0; s < NSEG; ++s) {
        // wait segment s landed (counted: seg s+1's 3 loads may stay in flight)
        if (s == NSEG - 1) { asm volatile("s_waitcnt vmcnt(0)" ::: "memory"); }
        else               { asm volatile("s_waitcnt vmcnt(3)" ::: "memory"); }
        asm volatile("" ::: "memory");
        __builtin_amdgcn_s_barrier();
        asm volatile("" ::: "memory");

        const char* bseg = smB + (s & 1) * SEGB + (kc << 11) + (lane << 4);
        half8 Bb0[3], Bb1[3];
        #pragma unroll
        for (int j = 0; j < 3; ++j) {
            Bb0[j] = *(const half8*)(bseg + j * 8192);
            Bb1[j] = *(const half8*)(bseg + j * 8192 + 1024);
        }
        #pragma unroll
        for (int j = 0; j < 3; ++j) {
            const int f = s * 3 + j;          // unroll-constant -> KT/LT fold to literals
            const int k = KT[f], l = LT[f];
            half8 a = (k == 0) ? xp[l - 1] : xp[k - 1] * xp[l - 1];
            acc0 = __builtin_amdgcn_mfma_f32_32x32x16_f16(a, Bb0[j], acc0, 0, 0, 0);
            acc1 = __builtin_amdgcn_mfma_f32_32x32x16_f16(a, Bb1[j], acc1, 0, 0, 0);
        }

        asm volatile("s_waitcnt lgkmcnt(0)" ::: "memory"); // my ds_reads retired
        asm volatile("" ::: "memory");
        __builtin_amdgcn_s_barrier();                      // everyone's retired
        asm volatile("" ::: "memory");
        if (s + 2 < NSEG) STAGE(s + 2);   // overwrite buf[s&1], just finished
    }
#undef STAGE

    __syncthreads(); // loop done; smx free for output staging
    float* os = (float*)smx; // [64 px][65]

    // reduce 4 kc partials (C/D: col=lane&31 (+nb*32), row=(r&3)+8*(r>>2)+4*lhi)
    #pragma unroll
    for (int pass = 0; pass < 4; ++pass) {
        if (kc == pass) {
            #pragma unroll
            for (int nb = 0; nb < 2; ++nb) {
                #pragma unroll
                for (int r = 0; r < 16; ++r) {
                    int row = (r & 3) + 8 * (r >> 2) + 4 * lhi;
                    int m = mwid * 32 + row;
                    int col = l31 + nb * 32;
                    float v = nb ? acc1[r] : acc0[r];
                    if (pass == 0) os[m * 65 + col] = v;
                    else           os[m * 65 + col] += v;
                }
            }
        }
        __syncthreads();
    }

    { // coalesced store: lanes sweep w
        const int w = t & 63;
        #pragma unroll
        for (int oo = 0; oo < 8; ++oo) {
            int o = wid * 8 + oo;
            float val = os[w * 65 + o] + fconst[o];
            out[(((size_t)b * POUT + o) * HH + hrow) * WW + w] = val;
        }
    }
}

// ---------------- fp32 fallback, used only if ws too small ----------------
__global__ __launch_bounds__(256) void poly2d_fp32(
    const float* __restrict__ x, const float* __restrict__ f,
    const float* __restrict__ bias, float* __restrict__ out)
{
    const int t = threadIdx.x;
    const int wo = t & 63;
    const int ho = (blockIdx.x & 15) * 4 + (t >> 6);
    const int o = (blockIdx.x >> 4) & 63;
    const int b = blockIdx.x >> 10;

    float acc = bias[o];
    const float* xb = x + (size_t)b * PIN * HH * WW;
    const float* fo = f + (size_t)o * PIN * 100;
    for (int c = 0; c < PIN; ++c) {
        const float* xc = xb + (size_t)c * HH * WW;
        float s[10];
        s[0] = 1.0f;
        #pragma unroll
        for (int kh = 0; kh < 3; ++kh) {
            int h = ho - 1 + kh;
            bool hok = ((unsigned)h < HH);
            #pragma unroll
            for (int kw = 0; kw < 3; ++kw) {
                int w = wo - 1 + kw;
                s[1 + kh * 3 + kw] = (hok && (unsigned)w < WW) ? xc[h * WW + w] : 0.0f;
            }
        }
        const float* fc = fo + c * 100;
        #pragma unroll
        for (int i = 0; i < 10; ++i) {
            float wsum = 0.0f;
            #pragma unroll
            for (int j = 0; j < 10; ++j) wsum = fmaf(fc[i * 10 + j], s[j], wsum);
            acc = fmaf(wsum, s[i], acc);
        }
    }
    out[(((size_t)b * POUT + o) * HH + ho) * WW + wo] = acc;
}

extern "C" void kernel_launch(void* const* d_in, const int* in_sizes, int n_in,
                              void* d_out, int out_size, void* d_ws, size_t ws_size,
                              hipStream_t stream) {
    const float* x    = (const float*)d_in[0];
    const float* filt = (const float*)d_in[1];
    const float* bias = (const float*)d_in[2];
    float* out = (float*)d_out;

    const size_t FPREP_BYTES = (size_t)NFEAT * POUT * PIN * 2; // 442368
    if (ws_size < FPREP_BYTES + 256) {
        poly2d_fp32<<<dim3(8 * 64 * 16), dim3(256), 0, stream>>>(x, filt, bias, out);
        return;
    }
    _Float16* fprep = (_Float16*)d_ws;
    float* fconst = (float*)((char*)d_ws + FPREP_BYTES);

    prep_filters<<<dim3(109), dim3(256), 0, stream>>>(filt, bias, fprep, fconst);
    poly2d_mfma<<<dim3(512), dim3(512), 0, stream>>>(x, fprep, fconst, out);
}